// Round 21
// baseline (248.109 us; speedup 1.0000x reference)
//
#include <hip/hip_runtime.h>
#include <hip/hip_bf16.h>

// Windowed MHA, B=16 C=128 H=W=128, WINDOW=64, heads=4, d=32.
// R21 = R20 inner phases, PERSISTENT blocks: grid 512 (= observed 2 blocks/CU
// residency), each block pipelines 8 consecutive windows through a
// double-buffered sX[2]:
//   iter wi: issue win(wi+1) global loads -> compute win(wi) [R20 phases] ->
//            pack+write sX[nxt] -> ONE barrier.
// HBM staging latency hides under compute; one cold start per 8 windows
// instead of per window. Consecutive windows are memory-contiguous (L2).

typedef __attribute__((ext_vector_type(8))) short bf16x8;
typedef __attribute__((ext_vector_type(4))) short bf16x4;
typedef __attribute__((ext_vector_type(4))) float f32x4;

#define MFMA32(A, B, C) __builtin_amdgcn_mfma_f32_16x16x32_bf16((A), (B), (C), 0, 0, 0)
#define MFMA16(A, B, C) __builtin_amdgcn_mfma_f32_16x16x16bf16_1k((A), (B), (C), 0, 0, 0)

__device__ __forceinline__ ushort f2bf(float f) {
    __hip_bfloat16 h = __float2bfloat16(f);       // RNE
    ushort u; __builtin_memcpy(&u, &h, 2); return u;
}
__device__ __forceinline__ unsigned pk2(float a, float b) {
    __hip_bfloat162 h = __float22bfloat162_rn(make_float2(a, b));  // lo=a, hi=b
    unsigned u; __builtin_memcpy(&u, &h, 4); return u;
}
__device__ __forceinline__ bf16x4 pk4(float a, float b, float c, float d) {
    uint2 u; u.x = pk2(a, b); u.y = pk2(c, d);
    bf16x4 r; __builtin_memcpy(&r, &u, 8); return r;
}
// 256B-row tile (sX): row bits 0-3 ^ bits 4-5 -> byte bits 4-7.
__device__ __forceinline__ int fsw(int row) { return ((row ^ (row >> 4)) & 15) << 4; }

__global__ void wconv(const float* __restrict__ Wq, const float* __restrict__ Wk,
                      const float* __restrict__ Wv, ushort* __restrict__ out) {
    int i = blockIdx.x * 256 + threadIdx.x;        // 16384 per matrix
    out[i]         = f2bf(Wq[i]);
    out[16384 + i] = f2bf(Wk[i]);
    out[32768 + i] = f2bf(Wv[i]);
}

__global__ __launch_bounds__(256, 2)
void attn_win(const float* __restrict__ x, const ushort* __restrict__ wbf,
              const float* __restrict__ bq, const float* __restrict__ bk,
              const float* __restrict__ bv, const float* __restrict__ Bb,
              float* __restrict__ out) {
    __shared__ __align__(16) char sX[2][16384];

    const int tid = threadIdx.x;
    const int w = tid >> 6;          // wave = head (0..3)
    const int l = tid & 63;
    const int lr = l & 15;
    const int lg = (l >> 4) & 3;
    const int g = blockIdx.x;        // 512 blocks x 8 windows
    const int win0 = g * 8;          // 8 | 256, so all 8 share batch b
    const long xbB = (long)(win0 >> 8) * 128 * 16384 + (long)(win0 & 255) * 64;

    const int cq_s = tid >> 4, t4_s = tid & 15;   // this thread's staging slot (x2)

    // ---- prologue: stage window 0 into sX[0] ----
    #pragma unroll
    for (int it = 0; it < 2; ++it) {
        int idx = it * 256 + tid;
        int cq = idx >> 4, t4 = idx & 15;
        const float* px = x + xbB + (long)(4 * cq) * 16384 + t4 * 4;
        float4 v0 = *(const float4*)(px);
        float4 v1 = *(const float4*)(px + 16384);
        float4 v2 = *(const float4*)(px + 32768);
        float4 v3 = *(const float4*)(px + 49152);
        float a0[4] = {v0.x, v0.y, v0.z, v0.w};
        float a1[4] = {v1.x, v1.y, v1.z, v1.w};
        float a2[4] = {v2.x, v2.y, v2.z, v2.w};
        float a3[4] = {v3.x, v3.y, v3.z, v3.w};
        #pragma unroll
        for (int jj = 0; jj < 4; ++jj) {
            int t = t4 * 4 + jj;
            uint2 pk;
            pk.x = pk2(a0[jj], a1[jj]);
            pk.y = pk2(a2[jj], a3[jj]);
            *(uint2*)(&sX[0][0] + t * 256 + ((8 * cq) ^ fsw(t))) = pk;
        }
    }
    __syncthreads();

    #pragma unroll 1
    for (int wi = 0; wi < 8; ++wi) {
        const int cur = wi & 1, nxt = cur ^ 1;
        const char* sXw = &sX[cur][0];
        const long xb = xbB + wi * 64;

        // ---- issue NEXT window's global loads (latency hides under compute) ----
        float4 pf[2][4];
        if (wi < 7) {
            #pragma unroll
            for (int it = 0; it < 2; ++it) {
                int idx = it * 256 + tid;
                int cq = idx >> 4, t4 = idx & 15;
                const float* px = x + xb + 64 + (long)(4 * cq) * 16384 + t4 * 4;
                pf[it][0] = *(const float4*)(px);
                pf[it][1] = *(const float4*)(px + 16384);
                pf[it][2] = *(const float4*)(px + 32768);
                pf[it][3] = *(const float4*)(px + 49152);
            }
        }

        // ---- Q,K,V projections fused, K=32 MFMA (R20) ----
        bf16x4 fQ[4][2], fK[4][2], fV[4][2];
        {
            f32x4 accQ[2][4], accK[2][4], accV[4][2];
            #pragma unroll
            for (int tn = 0; tn < 2; ++tn) {
                float4 bbq = *(const float4*)(bq + 32 * w + 16 * tn + 4 * lg);
                float4 bbk = *(const float4*)(bk + 32 * w + 16 * tn + 4 * lg);
                float bvv = bv[32 * w + 16 * tn + lr];
                #pragma unroll
                for (int tm = 0; tm < 4; ++tm) {
                    accQ[tn][tm] = (f32x4){bbq.x, bbq.y, bbq.z, bbq.w};
                    accK[tn][tm] = (f32x4){bbk.x, bbk.y, bbk.z, bbk.w};
                    accV[tm][tn] = (f32x4){bvv, bvv, bvv, bvv};
                }
            }
            #pragma unroll
            for (int kk = 0; kk < 4; ++kk) {
                bf16x8 aXk[4];
                #pragma unroll
                for (int tm = 0; tm < 4; ++tm) {
                    int row = 16 * tm + lr;
                    aXk[tm] = *(const bf16x8*)(sXw + row * 256
                                  + (((8 * lg + 32 * kk) * 2) ^ fsw(row)));
                }
                bf16x8 bWq[2], bWk[2], bWv[2];
                #pragma unroll
                for (int tn = 0; tn < 2; ++tn) {
                    int orow = (32 * w + 16 * tn + lr) * 128 + 8 * lg + 32 * kk;
                    bWq[tn] = *(const bf16x8*)(wbf + orow);
                    bWk[tn] = *(const bf16x8*)(wbf + 16384 + orow);
                    bWv[tn] = *(const bf16x8*)(wbf + 32768 + orow);
                }
                #pragma unroll
                for (int tn = 0; tn < 2; ++tn)
                    #pragma unroll
                    for (int tm = 0; tm < 4; ++tm) {
                        accQ[tn][tm] = MFMA32(bWq[tn], aXk[tm], accQ[tn][tm]);
                        accK[tn][tm] = MFMA32(bWk[tn], aXk[tm], accK[tn][tm]);
                        accV[tm][tn] = MFMA32(aXk[tm], bWv[tn], accV[tm][tn]);
                    }
            }
            #pragma unroll
            for (int tm = 0; tm < 4; ++tm)
                #pragma unroll
                for (int tn = 0; tn < 2; ++tn) {
                    fQ[tm][tn] = pk4(accQ[tn][tm][0], accQ[tn][tm][1],
                                     accQ[tn][tm][2], accQ[tn][tm][3]);
                    fK[tm][tn] = pk4(accK[tn][tm][0], accK[tn][tm][1],
                                     accK[tn][tm][2], accK[tn][tm][3]);
                    fV[tm][tn] = pk4(accV[tm][tn][0], accV[tm][tn][1],
                                     accV[tm][tn][2], accV[tm][tn][3]);
                }
        }

        // ---- scores^T (K=16) -> softmax -> P pack (R18) ----
        const float scale = 0.17677669529663687f;   // 1/sqrt(32)
        const float L2E = 1.4426950408889634f;
        bf16x4 pP[4][4];
        #pragma unroll
        for (int tmQ = 0; tmQ < 4; ++tmQ) {
            f32x4 sc[4];
            #pragma unroll
            for (int tmK = 0; tmK < 4; ++tmK) {
                sc[tmK] = (f32x4){0.f, 0.f, 0.f, 0.f};
                sc[tmK] = MFMA16(fK[tmK][0], fQ[tmQ][0], sc[tmK]);
                sc[tmK] = MFMA16(fK[tmK][1], fQ[tmQ][1], sc[tmK]);
            }
            int q = 16 * tmQ + lr;
            float s = 0.f;
            #pragma unroll
            for (int tmK = 0; tmK < 4; ++tmK) {
                float4 bb = *(const float4*)(Bb + q * 64 + 16 * tmK + 4 * lg);
                float e0 = exp2f((sc[tmK][0] * scale + bb.x) * L2E);
                float e1 = exp2f((sc[tmK][1] * scale + bb.y) * L2E);
                float e2 = exp2f((sc[tmK][2] * scale + bb.z) * L2E);
                float e3 = exp2f((sc[tmK][3] * scale + bb.w) * L2E);
                sc[tmK][0] = e0; sc[tmK][1] = e1;
                sc[tmK][2] = e2; sc[tmK][3] = e3;
                s += (e0 + e1) + (e2 + e3);
            }
            s += __shfl_xor(s, 16);
            s += __shfl_xor(s, 32);
            float rs = 1.0f / s;
            #pragma unroll
            for (int tmK = 0; tmK < 4; ++tmK)
                pP[tmK][tmQ] = pk4(sc[tmK][0] * rs, sc[tmK][1] * rs,
                                   sc[tmK][2] * rs, sc[tmK][3] * rs);
        }

        // ---- PV (K=16) ----
        f32x4 o[4][2];
        #pragma unroll
        for (int tmq = 0; tmq < 4; ++tmq)
            #pragma unroll
            for (int tn = 0; tn < 2; ++tn)
                o[tmq][tn] = (f32x4){0.f, 0.f, 0.f, 0.f};
        #pragma unroll
        for (int tmK = 0; tmK < 4; ++tmK)
            #pragma unroll
            for (int tmq = 0; tmq < 4; ++tmq)
                #pragma unroll
                for (int tn = 0; tn < 2; ++tn)
                    o[tmq][tn] = MFMA16(pP[tmK][tmq], fV[tmK][tn], o[tmq][tn]);

        // ---- stores ----
        #pragma unroll
        for (int tmq = 0; tmq < 4; ++tmq)
            #pragma unroll
            for (int tn = 0; tn < 2; ++tn) {
                int ch = 32 * w + 16 * tn + lr;
                int tok = 16 * tmq + 4 * lg;
                float4 ov;
                ov.x = o[tmq][tn][0];
                ov.y = o[tmq][tn][1];
                ov.z = o[tmq][tn][2];
                ov.w = o[tmq][tn][3];
                *(float4*)(out + xb + (long)ch * 16384 + tok) = ov;
            }

        // ---- pack + write NEXT window's buffer, then the ONE barrier ----
        if (wi < 7) {
            #pragma unroll
            for (int it = 0; it < 2; ++it) {
                int idx = it * 256 + tid;
                int cq = idx >> 4, t4 = idx & 15;
                float a0[4] = {pf[it][0].x, pf[it][0].y, pf[it][0].z, pf[it][0].w};
                float a1[4] = {pf[it][1].x, pf[it][1].y, pf[it][1].z, pf[it][1].w};
                float a2[4] = {pf[it][2].x, pf[it][2].y, pf[it][2].z, pf[it][2].w};
                float a3[4] = {pf[it][3].x, pf[it][3].y, pf[it][3].z, pf[it][3].w};
                #pragma unroll
                for (int jj = 0; jj < 4; ++jj) {
                    int t = t4 * 4 + jj;
                    uint2 pk;
                    pk.x = pk2(a0[jj], a1[jj]);
                    pk.y = pk2(a2[jj], a3[jj]);
                    *(uint2*)(&sX[nxt][0] + t * 256 + ((8 * cq) ^ fsw(t))) = pk;
                }
            }
        }
        __syncthreads();
    }
    (void)cq_s; (void)t4_s;
}

extern "C" void kernel_launch(void* const* d_in, const int* in_sizes, int n_in,
                              void* d_out, int out_size, void* d_ws, size_t ws_size,
                              hipStream_t stream) {
    const float* x  = (const float*)d_in[0];
    const float* Wq = (const float*)d_in[1];
    const float* bq = (const float*)d_in[2];
    const float* Wk = (const float*)d_in[3];
    const float* bk = (const float*)d_in[4];
    const float* Wv = (const float*)d_in[5];
    const float* bv = (const float*)d_in[6];
    const float* Bb = (const float*)d_in[7];
    float* out = (float*)d_out;
    ushort* wbf = (ushort*)d_ws;   // 3 x 128x128 bf16 = 96 KB

    wconv<<<64, 256, 0, stream>>>(Wq, Wk, Wv, wbf);
    attn_win<<<512, 256, 0, stream>>>(x, wbf, bq, bk, bv, Bb, out);
}

// Round 22
// 120.479 us; speedup vs baseline: 2.0594x; 2.0594x over previous
//
#include <hip/hip_runtime.h>
#include <hip/hip_bf16.h>

// Windowed MHA, B=16 C=128 H=W=128, WINDOW=64, heads=4, d=32.
// R22: ZERO LDS, ZERO BARRIERS. One wave = one (window, head), 4096 x 256thr.
// X fragments loaded directly from global fp32 (8 scalar dword loads per
// fragment, 64B-coalesced per 16-lane token group; 4 heads share the same
// 32KB window -> L1/L2 hits) and converted to bf16 in-register.
// Tests the ~2-blocks/CU residency cap (suspected LDS allocation granularity):
// with LDS=0, residency should rise to the VGPR limit if the theory is right.
// Projections fused K=32, attention K=16 consuming D-layouts directly (R18/R20).

typedef __attribute__((ext_vector_type(8))) short bf16x8;
typedef __attribute__((ext_vector_type(4))) short bf16x4;
typedef __attribute__((ext_vector_type(4))) float f32x4;

#define MFMA32(A, B, C) __builtin_amdgcn_mfma_f32_16x16x32_bf16((A), (B), (C), 0, 0, 0)
#define MFMA16(A, B, C) __builtin_amdgcn_mfma_f32_16x16x16bf16_1k((A), (B), (C), 0, 0, 0)

__device__ __forceinline__ ushort f2bf(float f) {
    __hip_bfloat16 h = __float2bfloat16(f);       // RNE
    ushort u; __builtin_memcpy(&u, &h, 2); return u;
}
__device__ __forceinline__ unsigned pk2(float a, float b) {
    __hip_bfloat162 h = __float22bfloat162_rn(make_float2(a, b));  // lo=a, hi=b
    unsigned u; __builtin_memcpy(&u, &h, 4); return u;
}
__device__ __forceinline__ bf16x4 pk4(float a, float b, float c, float d) {
    uint2 u; u.x = pk2(a, b); u.y = pk2(c, d);
    bf16x4 r; __builtin_memcpy(&r, &u, 8); return r;
}

__global__ void wconv(const float* __restrict__ Wq, const float* __restrict__ Wk,
                      const float* __restrict__ Wv, ushort* __restrict__ out) {
    int i = blockIdx.x * 256 + threadIdx.x;        // 16384 per matrix
    out[i]         = f2bf(Wq[i]);
    out[16384 + i] = f2bf(Wk[i]);
    out[32768 + i] = f2bf(Wv[i]);
}

__global__ __launch_bounds__(256, 2)
void attn_win(const float* __restrict__ x, const ushort* __restrict__ wbf,
              const float* __restrict__ bq, const float* __restrict__ bk,
              const float* __restrict__ bv, const float* __restrict__ Bb,
              float* __restrict__ out) {
    const int tid = threadIdx.x;
    const int w = tid >> 6;          // wave = head (0..3)
    const int l = tid & 63;
    const int lr = l & 15;
    const int lg = (l >> 4) & 3;
    const int blk = blockIdx.x;
    const int b = blk >> 8, n = blk & 255;
    const long xbase = (long)b * 128 * 16384 + n * 64;

    // ---- Q,K,V projections FUSED, K=32 MFMA; X fragments from GLOBAL ----
    // Q,K: W.X^T -> D[och 4lg+r][tok lr]  (A=W, B=X)
    // V:   X.W^T -> D[tok 4lg+r][och lr]  (A=X, B=W)
    bf16x4 fQ[4][2], fK[4][2], fV[4][2];
    {
        f32x4 accQ[2][4], accK[2][4], accV[4][2];
        #pragma unroll
        for (int tn = 0; tn < 2; ++tn) {
            float4 bbq = *(const float4*)(bq + 32 * w + 16 * tn + 4 * lg);
            float4 bbk = *(const float4*)(bk + 32 * w + 16 * tn + 4 * lg);
            float bvv = bv[32 * w + 16 * tn + lr];
            #pragma unroll
            for (int tm = 0; tm < 4; ++tm) {
                accQ[tn][tm] = (f32x4){bbq.x, bbq.y, bbq.z, bbq.w};
                accK[tn][tm] = (f32x4){bbk.x, bbk.y, bbk.z, bbk.w};
                accV[tm][tn] = (f32x4){bvv, bvv, bvv, bvv};
            }
        }
        #pragma unroll
        for (int kk = 0; kk < 4; ++kk) {
            // X fragment: lane (lr,lg) of tile tm = token 16tm+lr,
            // channels 8lg+32kk..+7 -> 8 strided dword loads, pack to bf16x8.
            bf16x8 aXk[4];
            #pragma unroll
            for (int tm = 0; tm < 4; ++tm) {
                const float* px = x + xbase + (long)(8 * lg + 32 * kk) * 16384
                                  + 16 * tm + lr;
                float v0 = px[0];
                float v1 = px[16384];
                float v2 = px[2 * 16384];
                float v3 = px[3 * 16384];
                float v4 = px[4 * 16384];
                float v5 = px[5 * 16384];
                float v6 = px[6 * 16384];
                float v7 = px[7 * 16384];
                int4 wv;
                wv.x = (int)pk2(v0, v1);
                wv.y = (int)pk2(v2, v3);
                wv.z = (int)pk2(v4, v5);
                wv.w = (int)pk2(v6, v7);
                aXk[tm] = *(bf16x8*)&wv;
            }
            bf16x8 bWq[2], bWk[2], bWv[2];
            #pragma unroll
            for (int tn = 0; tn < 2; ++tn) {
                int orow = (32 * w + 16 * tn + lr) * 128 + 8 * lg + 32 * kk;
                bWq[tn] = *(const bf16x8*)(wbf + orow);
                bWk[tn] = *(const bf16x8*)(wbf + 16384 + orow);
                bWv[tn] = *(const bf16x8*)(wbf + 32768 + orow);
            }
            #pragma unroll
            for (int tn = 0; tn < 2; ++tn)
                #pragma unroll
                for (int tm = 0; tm < 4; ++tm) {
                    accQ[tn][tm] = MFMA32(bWq[tn], aXk[tm], accQ[tn][tm]);
                    accK[tn][tm] = MFMA32(bWk[tn], aXk[tm], accK[tn][tm]);
                    accV[tm][tn] = MFMA32(aXk[tm], bWv[tn], accV[tm][tn]);
                }
        }
        #pragma unroll
        for (int tm = 0; tm < 4; ++tm)
            #pragma unroll
            for (int tn = 0; tn < 2; ++tn) {
                fQ[tm][tn] = pk4(accQ[tn][tm][0], accQ[tn][tm][1],
                                 accQ[tn][tm][2], accQ[tn][tm][3]);
                fK[tm][tn] = pk4(accK[tn][tm][0], accK[tn][tm][1],
                                 accK[tn][tm][2], accK[tn][tm][3]);
                fV[tm][tn] = pk4(accV[tm][tn][0], accV[tm][tn][1],
                                 accV[tm][tn][2], accV[tm][tn][3]);
            }
    }

    // ---- per-tmQ: scores^T = K=16 mfma(A=fK, B=fQ) -> softmax -> pack P ----
    // D[k 16tmK+4lg+r][q 16tmQ+lr]; P pack is directly the PV A-fragment.
    const float scale = 0.17677669529663687f;   // 1/sqrt(32)
    const float L2E = 1.4426950408889634f;
    bf16x4 pP[4][4];   // [tmK][tmQ]
    #pragma unroll
    for (int tmQ = 0; tmQ < 4; ++tmQ) {
        f32x4 sc[4];
        #pragma unroll
        for (int tmK = 0; tmK < 4; ++tmK) {
            sc[tmK] = (f32x4){0.f, 0.f, 0.f, 0.f};
            sc[tmK] = MFMA16(fK[tmK][0], fQ[tmQ][0], sc[tmK]);
            sc[tmK] = MFMA16(fK[tmK][1], fQ[tmQ][1], sc[tmK]);
        }
        int q = 16 * tmQ + lr;
        float s = 0.f;
        #pragma unroll
        for (int tmK = 0; tmK < 4; ++tmK) {
            float4 bb = *(const float4*)(Bb + q * 64 + 16 * tmK + 4 * lg);
            float e0 = exp2f((sc[tmK][0] * scale + bb.x) * L2E);
            float e1 = exp2f((sc[tmK][1] * scale + bb.y) * L2E);
            float e2 = exp2f((sc[tmK][2] * scale + bb.z) * L2E);
            float e3 = exp2f((sc[tmK][3] * scale + bb.w) * L2E);
            sc[tmK][0] = e0; sc[tmK][1] = e1;
            sc[tmK][2] = e2; sc[tmK][3] = e3;
            s += (e0 + e1) + (e2 + e3);
        }
        s += __shfl_xor(s, 16);
        s += __shfl_xor(s, 32);
        float rs = 1.0f / s;
        #pragma unroll
        for (int tmK = 0; tmK < 4; ++tmK)
            pP[tmK][tmQ] = pk4(sc[tmK][0] * rs, sc[tmK][1] * rs,
                               sc[tmK][2] * rs, sc[tmK][3] * rs);
    }

    // ---- PV: K=16 mfma(A=pP, B=fV); D[q 4lg+r][d lr] ----
    f32x4 o[4][2];
    #pragma unroll
    for (int tmq = 0; tmq < 4; ++tmq)
        #pragma unroll
        for (int tn = 0; tn < 2; ++tn)
            o[tmq][tn] = (f32x4){0.f, 0.f, 0.f, 0.f};
    #pragma unroll
    for (int tmK = 0; tmK < 4; ++tmK)
        #pragma unroll
        for (int tmq = 0; tmq < 4; ++tmq)
            #pragma unroll
            for (int tn = 0; tn < 2; ++tn)
                o[tmq][tn] = MFMA16(pP[tmK][tmq], fV[tmK][tn], o[tmq][tn]);

    // ---- direct coalesced float4 stores (4 consecutive tokens per reg) ----
    #pragma unroll
    for (int tmq = 0; tmq < 4; ++tmq)
        #pragma unroll
        for (int tn = 0; tn < 2; ++tn) {
            int ch = 32 * w + 16 * tn + lr;
            int tok = 16 * tmq + 4 * lg;
            float4 ov;
            ov.x = o[tmq][tn][0];
            ov.y = o[tmq][tn][1];
            ov.z = o[tmq][tn][2];
            ov.w = o[tmq][tn][3];
            *(float4*)(out + xbase + (long)ch * 16384 + tok) = ov;
        }
}

extern "C" void kernel_launch(void* const* d_in, const int* in_sizes, int n_in,
                              void* d_out, int out_size, void* d_ws, size_t ws_size,
                              hipStream_t stream) {
    const float* x  = (const float*)d_in[0];
    const float* Wq = (const float*)d_in[1];
    const float* bq = (const float*)d_in[2];
    const float* Wk = (const float*)d_in[3];
    const float* bk = (const float*)d_in[4];
    const float* Wv = (const float*)d_in[5];
    const float* bv = (const float*)d_in[6];
    const float* Bb = (const float*)d_in[7];
    float* out = (float*)d_out;
    ushort* wbf = (ushort*)d_ws;   // 3 x 128x128 bf16 = 96 KB

    wconv<<<64, 256, 0, stream>>>(Wq, Wk, Wv, wbf);
    attn_win<<<4096, 256, 0, stream>>>(x, wbf, bq, bk, bv, Bb, out);
}